// Round 3
// baseline (364.663 us; speedup 1.0000x reference)
//
#include <hip/hip_runtime.h>
#include <math.h>

#define NUM_EMB 1024
#define EMB_DIM 256
#define N_ROWS  65536
#define HW      1024
#define QUANT_OFF 1
#define IDX_OFF   (1 + 16777216)
#define LDA 264   // halfs per A-row in LDS (256 + 8 pad)

typedef unsigned int uint;
typedef _Float16 f16x8 __attribute__((ext_vector_type(8)));
typedef float    f32x4 __attribute__((ext_vector_type(4)));

__device__ __forceinline__ uint umin2(uint a, uint b) { return a < b ? a : b; }
__device__ __forceinline__ uint umax2(uint a, uint b) { return a > b ? a : b; }

// ---------------- kernel 1: normalize codebook (f32 + f16 copies) ----------------
__global__ __launch_bounds__(256)
void k_norm_w(const float* __restrict__ w, float* __restrict__ wn, _Float16* __restrict__ wh) {
  const int k = blockIdx.x, t = threadIdx.x;
  const float v = w[(size_t)k * EMB_DIM + t];
  float s = v * v;
  for (int o = 32; o; o >>= 1) s += __shfl_down(s, o);
  __shared__ float ps[4];
  if ((t & 63) == 0) ps[t >> 6] = s;
  __syncthreads();
  const float tot = ps[0] + ps[1] + ps[2] + ps[3];
  const float nv = v / fmaxf(sqrtf(tot), 1e-12f);
  wn[(size_t)k * EMB_DIM + t] = nv;
  wh[(size_t)k * EMB_DIM + t] = (_Float16)nv;
}

// ---------------- kernel 2: fp16 MFMA score GEMM + per-row top-4 candidates ----------------
// 4 waves; wave tile 64 rows x 32 codes; 8 chunks of 128 codes cover K=1024 codes.
// Registers: acc 32 + frags ~32 + top2 32 -> fits 128 total => 4 waves/SIMD.
__global__ __launch_bounds__(256, 4)
void k_pass1(const float* __restrict__ x, const _Float16* __restrict__ wh,
             uint* __restrict__ cand) {
  __shared__ __align__(16) _Float16 As[64 * LDA];   // 33792 B
  const int t = threadIdx.x;
  const int blk = blockIdx.x;
  const int b = blk >> 4;
  const int hw0 = (blk & 15) * 64;

  // ---- stage A: x[b, d, hw0+r] f32 -> As[r][d] f16 ----
  {
    const int lhw = t & 63;
    const int ph = t >> 6;
    const float* xb = x + (size_t)b * (EMB_DIM * HW) + hw0 + lhw;
#pragma unroll 8
    for (int j = 0; j < 64; ++j) {
      const int d = ph + j * 4;
      As[lhw * LDA + d] = (_Float16)xb[(size_t)d * HW];
    }
  }
  __syncthreads();

  const int lane = t & 63;
  const int q = lane >> 4;
  const int l15 = lane & 15;
  const int w = t >> 6;

  uint t1[16], t2[16];
#pragma unroll
  for (int i = 0; i < 16; ++i) { t1[i] = 0u; t2[i] = 0u; }

  const int abase = l15 * LDA + q * 8;
  const _Float16* pb = wh + (size_t)(w * 32 + l15) * EMB_DIM + q * 8;

  for (int c8 = 0; c8 < 8; ++c8) {
    f32x4 acc[4][2];
#pragma unroll
    for (int rt = 0; rt < 4; ++rt) { acc[rt][0] = (f32x4)0.f; acc[rt][1] = (f32x4)0.f; }

    const _Float16* p0 = pb + (size_t)(c8 * 128) * EMB_DIM;
    const _Float16* p1 = p0 + 16 * EMB_DIM;
    f16x8 b0 = *(const f16x8*)p0;
    f16x8 b1 = *(const f16x8*)p1;

#pragma unroll
    for (int ks = 0; ks < 8; ++ks) {
      f16x8 n0, n1;
      if (ks < 7) {
        n0 = *(const f16x8*)(p0 + (ks + 1) * 32);
        n1 = *(const f16x8*)(p1 + (ks + 1) * 32);
      }
      const f16x8 a0 = *(const f16x8*)&As[abase + 0 * 16 * LDA + ks * 32];
      const f16x8 a1 = *(const f16x8*)&As[abase + 1 * 16 * LDA + ks * 32];
      const f16x8 a2 = *(const f16x8*)&As[abase + 2 * 16 * LDA + ks * 32];
      const f16x8 a3 = *(const f16x8*)&As[abase + 3 * 16 * LDA + ks * 32];
      acc[0][0] = __builtin_amdgcn_mfma_f32_16x16x32_f16(a0, b0, acc[0][0], 0, 0, 0);
      acc[1][0] = __builtin_amdgcn_mfma_f32_16x16x32_f16(a1, b0, acc[1][0], 0, 0, 0);
      acc[2][0] = __builtin_amdgcn_mfma_f32_16x16x32_f16(a2, b0, acc[2][0], 0, 0, 0);
      acc[3][0] = __builtin_amdgcn_mfma_f32_16x16x32_f16(a3, b0, acc[3][0], 0, 0, 0);
      acc[0][1] = __builtin_amdgcn_mfma_f32_16x16x32_f16(a0, b1, acc[0][1], 0, 0, 0);
      acc[1][1] = __builtin_amdgcn_mfma_f32_16x16x32_f16(a1, b1, acc[1][1], 0, 0, 0);
      acc[2][1] = __builtin_amdgcn_mfma_f32_16x16x32_f16(a2, b1, acc[2][1], 0, 0, 0);
      acc[3][1] = __builtin_amdgcn_mfma_f32_16x16x32_f16(a3, b1, acc[3][1], 0, 0, 0);
      if (ks < 7) { b0 = n0; b1 = n1; }
    }

    // merge into per-(lane,slot) top-2 packed keys (score hi-bits | idx)
#pragma unroll
    for (int ct = 0; ct < 2; ++ct) {
      const uint idxv = (uint)(c8 * 128 + w * 32 + ct * 16 + l15);
#pragma unroll
      for (int rt = 0; rt < 4; ++rt)
#pragma unroll
        for (int r = 0; r < 4; ++r) {
          const float v = fmaxf(acc[rt][ct][r], 0.0f);
          const uint key = (__float_as_uint(v) & 0xFFFFFC00u) | idxv;
          const int slot = rt * 4 + r;
          const uint lo = umin2(key, t1[slot]);
          t1[slot] = umax2(key, t1[slot]);
          t2[slot] = umax2(t2[slot], lo);
        }
    }
  }

  // ---- block-level per-row top-4 (reuse A LDS as key scratch) ----
  __syncthreads();
  uint* keys = (uint*)As;   // [64 rows][128 keys] = 32 KB
#pragma unroll
  for (int slot = 0; slot < 16; ++slot) {
    const int rt = slot >> 2, r = slot & 3;
    const int row = rt * 16 + q * 4 + r;
    const int col = w * 32 + l15 * 2;
    keys[row * 128 + col] = t1[slot];
    keys[row * 128 + col + 1] = t2[slot];
  }
  __syncthreads();
  {
    const int row = t >> 2, seg = t & 3;     // 4 threads per row, 32 keys each
    uint s1 = 0, s2 = 0;
#pragma unroll
    for (int i = 0; i < 8; ++i) {
      const int ii = (i + t) & 7;
      const uint4 k4 = *(const uint4*)&keys[row * 128 + seg * 32 + ii * 4];
      const uint kk[4] = {k4.x, k4.y, k4.z, k4.w};
#pragma unroll
      for (int e = 0; e < 4; ++e) {
        const uint lo = umin2(kk[e], s1);
        s1 = umax2(kk[e], s1);
        s2 = umax2(s2, lo);
      }
    }
    __syncthreads();
    keys[t * 2] = s1;
    keys[t * 2 + 1] = s2;
  }
  __syncthreads();
  if (t < 64) {
    uint c0 = 0, c1 = 0, c2 = 0, c3 = 0;
#pragma unroll
    for (int i = 0; i < 8; ++i) {
      const uint k = keys[t * 8 + i];
      const uint n0 = umin2(c0, k); c0 = umax2(c0, k);
      const uint n1 = umin2(c1, n0); c1 = umax2(c1, n0);
      const uint n2 = umin2(c2, n1); c2 = umax2(c2, n1);
      c3 = umax2(c3, n2);
    }
    uint4 o; o.x = c0; o.y = c1; o.z = c2; o.w = c3;
    *(uint4*)&cand[(size_t)(blk * 64 + t) * 4] = o;
  }
}

// ------- kernel 3: fp64 recheck (coalesced), idx + loss + quant via LDS transpose -------
// 4096 blocks x 256 thr; block = 16 rows; row owned by a 16-lane group.
__global__ __launch_bounds__(256, 4)
void k_finish(const float* __restrict__ x, const float* __restrict__ w,
              const float* __restrict__ wn, const uint* __restrict__ cand,
              float* __restrict__ out) {
  __shared__ float xs[16][260];        // 16.6 KB  [row][d], pad 4
  __shared__ float qs[256 * 17];       // 17.4 KB  [d][row], stride 17
  __shared__ int cw_s[16];
  __shared__ double lsum[4];
  const int t = threadIdx.x;
  const int blk = blockIdx.x;          // 4096
  const int b = blk >> 6;
  const int hw0 = (blk & 63) * 16;

  // ---- stage x tile [16 rows][256 d] (coalesced per-d global reads) ----
  {
    const int r = t & 15, dp = t >> 4;
    const float* xb = x + (size_t)b * (EMB_DIM * HW) + hw0 + r;
#pragma unroll
    for (int j = 0; j < 16; ++j) {
      const int d = dp * 16 + j;
      xs[r][d] = xb[(size_t)d * HW];
    }
  }
  __syncthreads();

  const int row = t >> 4;              // 0..15
  const int li = t & 15;
  const int n0 = blk * 16 + row;
  const uint4 ck = *(const uint4*)&cand[(size_t)n0 * 4];
  const uint cv[4] = {ck.x, ck.y, ck.z, ck.w};

  float4 xf[4];
#pragma unroll
  for (int k = 0; k < 4; ++k) xf[k] = *(const float4*)&xs[row][k * 64 + li * 4];

  double sxx = 0.0;
#pragma unroll
  for (int k = 0; k < 4; ++k) {
    const float xv[4] = {xf[k].x, xf[k].y, xf[k].z, xf[k].w};
#pragma unroll
    for (int e = 0; e < 4; ++e) sxx = fma((double)xv[e], (double)xv[e], sxx);
  }

  double sj[4], aj[4];
#pragma unroll
  for (int j = 0; j < 4; ++j) {
    const int c = (int)(cv[j] & 1023u);
    const float* wr = w + (size_t)c * EMB_DIM;
    double s = 0.0, a = 0.0;
#pragma unroll
    for (int k = 0; k < 4; ++k) {
      const float4 w4 = *(const float4*)&wr[k * 64 + li * 4];   // 16-lane contig 256B
      const float xv[4] = {xf[k].x, xf[k].y, xf[k].z, xf[k].w};
      const float wv[4] = {w4.x, w4.y, w4.z, w4.w};
#pragma unroll
      for (int e = 0; e < 4; ++e) {
        s = fma((double)xv[e], (double)wv[e], s);
        a = fma((double)wv[e], (double)wv[e], a);
      }
    }
    sj[j] = s; aj[j] = a;
  }

  // reduce within the 16-lane group (valid at li==0)
#pragma unroll
  for (int o = 8; o; o >>= 1) {
    sxx += __shfl_down(sxx, o);
#pragma unroll
    for (int j = 0; j < 4; ++j) {
      sj[j] += __shfl_down(sj[j], o);
      aj[j] += __shfl_down(aj[j], o);
    }
  }

  double dmin = 0.0;
  if (li == 0) {
    double qbest = -1e300; int cw = 1 << 30;
#pragma unroll
    for (int j = 0; j < 4; ++j) {
      const int c = (int)(cv[j] & 1023u);
      const double qj = sj[j] / fmax(sqrt(aj[j]), 1e-12);
      if (qj > qbest || (qj == qbest && c < cw)) { qbest = qj; cw = c; }
    }
    dmin = 2.0 - 2.0 * qbest / fmax(sqrt(sxx), 1e-12);   // exact dist of winner
    out[IDX_OFF + n0] = (float)cw;
    cw_s[row] = cw;
  }

  // loss partial: wave then block reduce, one atomic
  double v = dmin;
  for (int o = 32; o; o >>= 1) v += __shfl_down(v, o);
  if ((t & 63) == 0) lsum[t >> 6] = v;
  __syncthreads();
  if (t == 0)
    atomicAdd(out, (float)(1.25 * (lsum[0] + lsum[1] + lsum[2] + lsum[3]) / 16777216.0));

  // ---- quant: gather wn[cw] rows (16-lane coalesced) -> qs[d][row] -> coalesced store ----
  {
    const int c = cw_s[row];
    const float* wr = wn + (size_t)c * EMB_DIM;
#pragma unroll
    for (int k = 0; k < 4; ++k) {
      const int d0 = k * 64 + li * 4;
      const float4 w4 = *(const float4*)&wr[d0];
      qs[(d0 + 0) * 17 + row] = w4.x;
      qs[(d0 + 1) * 17 + row] = w4.y;
      qs[(d0 + 2) * 17 + row] = w4.z;
      qs[(d0 + 3) * 17 + row] = w4.w;
    }
  }
  __syncthreads();
  {
    const int r = t & 15, dg = t >> 4;
    float* qout = out + QUANT_OFF + (size_t)b * (EMB_DIM * HW) + hw0 + r;
#pragma unroll
    for (int j = 0; j < 16; ++j) {
      const int d = dg * 16 + j;
      qout[(size_t)d * HW] = qs[d * 17 + r];
    }
  }
}

extern "C" void kernel_launch(void* const* d_in, const int* in_sizes, int n_in,
                              void* d_out, int out_size, void* d_ws, size_t ws_size,
                              hipStream_t stream) {
  const float* x = (const float*)d_in[0];   // [64,256,32,32]
  const float* w = (const float*)d_in[1];   // [1024,256]
  float* out = (float*)d_out;               // [1 + 16777216 + 65536] f32

  char* ws = (char*)d_ws;
  float*     wn   = (float*)ws;                      // 1 MB
  _Float16*  wh   = (_Float16*)(ws + 1048576);       // 512 KB
  uint*      cand = (uint*)(ws + 1048576 + 524288);  // 1 MB

  hipMemsetAsync(d_out, 0, sizeof(float), stream);   // zero loss accumulator
  hipLaunchKernelGGL(k_norm_w, dim3(NUM_EMB), dim3(256), 0, stream, w, wn, wh);
  hipLaunchKernelGGL(k_pass1, dim3(N_ROWS / 64), dim3(256), 0, stream, x, wh, cand);
  hipLaunchKernelGGL(k_finish, dim3(N_ROWS / 16), dim3(256), 0, stream, x, w, wn, cand, out);
}

// Round 4
// 320.859 us; speedup vs baseline: 1.1365x; 1.1365x over previous
//
#include <hip/hip_runtime.h>
#include <math.h>

#define NUM_EMB 1024
#define EMB_DIM 256
#define N_ROWS  65536
#define HW      1024
#define QUANT_OFF 1
#define IDX_OFF   (1 + 16777216)
#define LDA 264   // halfs per A-row in LDS (256 + 8 pad)

typedef unsigned int uint;
typedef _Float16 f16x8 __attribute__((ext_vector_type(8)));
typedef float    f32x4 __attribute__((ext_vector_type(4)));

__device__ __forceinline__ uint umin2(uint a, uint b) { return a < b ? a : b; }
__device__ __forceinline__ uint umax2(uint a, uint b) { return a > b ? a : b; }

// ---------------- kernel 1: normalize codebook (f32 + f16 copies) ----------------
__global__ __launch_bounds__(256)
void k_norm_w(const float* __restrict__ w, float* __restrict__ wn, _Float16* __restrict__ wh) {
  const int k = blockIdx.x, t = threadIdx.x;
  const float v = w[(size_t)k * EMB_DIM + t];
  float s = v * v;
  for (int o = 32; o; o >>= 1) s += __shfl_down(s, o);
  __shared__ float ps[4];
  if ((t & 63) == 0) ps[t >> 6] = s;
  __syncthreads();
  const float tot = ps[0] + ps[1] + ps[2] + ps[3];
  const float nv = v / fmaxf(sqrtf(tot), 1e-12f);
  wn[(size_t)k * EMB_DIM + t] = nv;
  wh[(size_t)k * EMB_DIM + t] = (_Float16)nv;
}

// ---------------- kernel 2: fp16 MFMA score GEMM + per-row top-4 candidates ----------------
// R2 structure (64 rows x 64 codes per wave, 4 chunks of 256 codes), explicit prefetch
// regs removed so __launch_bounds__(256,3) fits WITHOUT scratch spills (R3 lesson).
__global__ __launch_bounds__(256, 3)
void k_pass1(const float* __restrict__ x, const _Float16* __restrict__ wh,
             uint* __restrict__ cand) {
  __shared__ __align__(16) _Float16 As[64 * LDA];   // 33792 B
  const int t = threadIdx.x;
  const int blk = blockIdx.x;
  const int b = blk >> 4;
  const int hw0 = (blk & 15) * 64;

  // ---- stage A: x[b, d, hw0+r] f32 -> As[r][d] f16 ----
  {
    const int lhw = t & 63;
    const int ph = t >> 6;
    const float* xb = x + (size_t)b * (EMB_DIM * HW) + hw0 + lhw;
#pragma unroll 8
    for (int j = 0; j < 64; ++j) {
      const int d = ph + j * 4;
      As[lhw * LDA + d] = (_Float16)xb[(size_t)d * HW];
    }
  }
  __syncthreads();

  const int lane = t & 63;
  const int q = lane >> 4;
  const int l15 = lane & 15;
  const int w = t >> 6;

  uint t1[16], t2[16];
#pragma unroll
  for (int i = 0; i < 16; ++i) { t1[i] = 0u; t2[i] = 0u; }

  const _Float16* pb = wh + (size_t)(w * 64 + l15) * EMB_DIM + q * 8;

  for (int c4 = 0; c4 < 4; ++c4) {
    f32x4 acc[4][4];
#pragma unroll
    for (int rt = 0; rt < 4; ++rt)
#pragma unroll
      for (int ct = 0; ct < 4; ++ct) acc[rt][ct] = (f32x4)0.f;

    const _Float16* pc0 = pb + (size_t)(c4 * 256 +  0) * EMB_DIM;
    const _Float16* pc1 = pb + (size_t)(c4 * 256 + 16) * EMB_DIM;
    const _Float16* pc2 = pb + (size_t)(c4 * 256 + 32) * EMB_DIM;
    const _Float16* pc3 = pb + (size_t)(c4 * 256 + 48) * EMB_DIM;

#pragma unroll
    for (int ks = 0; ks < 8; ++ks) {
      const int off = ks * 32;
      const f16x8 b0 = *(const f16x8*)(pc0 + off);
      const f16x8 b1 = *(const f16x8*)(pc1 + off);
      const f16x8 b2 = *(const f16x8*)(pc2 + off);
      const f16x8 b3 = *(const f16x8*)(pc3 + off);
      const f16x8 a0 = *(const f16x8*)&As[(0 * 16 + l15) * LDA + off + q * 8];
      const f16x8 a1 = *(const f16x8*)&As[(1 * 16 + l15) * LDA + off + q * 8];
      const f16x8 a2 = *(const f16x8*)&As[(2 * 16 + l15) * LDA + off + q * 8];
      const f16x8 a3 = *(const f16x8*)&As[(3 * 16 + l15) * LDA + off + q * 8];
      acc[0][0] = __builtin_amdgcn_mfma_f32_16x16x32_f16(a0, b0, acc[0][0], 0, 0, 0);
      acc[1][0] = __builtin_amdgcn_mfma_f32_16x16x32_f16(a1, b0, acc[1][0], 0, 0, 0);
      acc[2][0] = __builtin_amdgcn_mfma_f32_16x16x32_f16(a2, b0, acc[2][0], 0, 0, 0);
      acc[3][0] = __builtin_amdgcn_mfma_f32_16x16x32_f16(a3, b0, acc[3][0], 0, 0, 0);
      acc[0][1] = __builtin_amdgcn_mfma_f32_16x16x32_f16(a0, b1, acc[0][1], 0, 0, 0);
      acc[1][1] = __builtin_amdgcn_mfma_f32_16x16x32_f16(a1, b1, acc[1][1], 0, 0, 0);
      acc[2][1] = __builtin_amdgcn_mfma_f32_16x16x32_f16(a2, b1, acc[2][1], 0, 0, 0);
      acc[3][1] = __builtin_amdgcn_mfma_f32_16x16x32_f16(a3, b1, acc[3][1], 0, 0, 0);
      acc[0][2] = __builtin_amdgcn_mfma_f32_16x16x32_f16(a0, b2, acc[0][2], 0, 0, 0);
      acc[1][2] = __builtin_amdgcn_mfma_f32_16x16x32_f16(a1, b2, acc[1][2], 0, 0, 0);
      acc[2][2] = __builtin_amdgcn_mfma_f32_16x16x32_f16(a2, b2, acc[2][2], 0, 0, 0);
      acc[3][2] = __builtin_amdgcn_mfma_f32_16x16x32_f16(a3, b2, acc[3][2], 0, 0, 0);
      acc[0][3] = __builtin_amdgcn_mfma_f32_16x16x32_f16(a0, b3, acc[0][3], 0, 0, 0);
      acc[1][3] = __builtin_amdgcn_mfma_f32_16x16x32_f16(a1, b3, acc[1][3], 0, 0, 0);
      acc[2][3] = __builtin_amdgcn_mfma_f32_16x16x32_f16(a2, b3, acc[2][3], 0, 0, 0);
      acc[3][3] = __builtin_amdgcn_mfma_f32_16x16x32_f16(a3, b3, acc[3][3], 0, 0, 0);
    }

    // merge into per-(lane,slot) top-2 packed keys (score hi-bits | idx)
#pragma unroll
    for (int ct = 0; ct < 4; ++ct) {
      const uint idxv = (uint)(c4 * 256 + w * 64 + ct * 16 + l15);
#pragma unroll
      for (int rt = 0; rt < 4; ++rt)
#pragma unroll
        for (int r = 0; r < 4; ++r) {
          const float v = fmaxf(acc[rt][ct][r], 0.0f);
          const uint key = (__float_as_uint(v) & 0xFFFFFC00u) | idxv;
          const int slot = rt * 4 + r;
          const uint lo = umin2(key, t1[slot]);
          t1[slot] = umax2(key, t1[slot]);
          t2[slot] = umax2(t2[slot], lo);
        }
    }
  }

  // ---- block-level per-row top-4 (reuse A LDS as key scratch) ----
  __syncthreads();
  uint* keys = (uint*)As;   // [64 rows][128 keys] = 32 KB
#pragma unroll
  for (int slot = 0; slot < 16; ++slot) {
    const int rt = slot >> 2, r = slot & 3;
    const int row = rt * 16 + q * 4 + r;
    const int col = w * 32 + l15 * 2;
    keys[row * 128 + col] = t1[slot];
    keys[row * 128 + col + 1] = t2[slot];
  }
  __syncthreads();
  {
    const int row = t >> 2, seg = t & 3;     // 4 threads per row, 32 keys each
    uint s1 = 0, s2 = 0;
#pragma unroll
    for (int i = 0; i < 8; ++i) {
      const int ii = (i + t) & 7;
      const uint4 k4 = *(const uint4*)&keys[row * 128 + seg * 32 + ii * 4];
      const uint kk[4] = {k4.x, k4.y, k4.z, k4.w};
#pragma unroll
      for (int e = 0; e < 4; ++e) {
        const uint lo = umin2(kk[e], s1);
        s1 = umax2(kk[e], s1);
        s2 = umax2(s2, lo);
      }
    }
    __syncthreads();
    keys[t * 2] = s1;
    keys[t * 2 + 1] = s2;
  }
  __syncthreads();
  if (t < 64) {
    uint c0 = 0, c1 = 0, c2 = 0, c3 = 0;
#pragma unroll
    for (int i = 0; i < 8; ++i) {
      const uint k = keys[t * 8 + i];
      const uint n0 = umin2(c0, k); c0 = umax2(c0, k);
      const uint n1 = umin2(c1, n0); c1 = umax2(c1, n0);
      const uint n2 = umin2(c2, n1); c2 = umax2(c2, n1);
      c3 = umax2(c3, n2);
    }
    uint4 o; o.x = c0; o.y = c1; o.z = c2; o.w = c3;
    *(uint4*)&cand[(size_t)(blk * 64 + t) * 4] = o;
  }
}

// ------- kernel 3: fp64 recheck, full-cache-line accesses everywhere -------
// 2048 blocks x 256 thr; 32 rows/block; 8 lanes per row.
#define XSTR 257   // floats per row in xs scratch (bank-friendly)
__global__ __launch_bounds__(256)
void k_finish(const float* __restrict__ x, const float* __restrict__ w,
              const float* __restrict__ wn, const uint* __restrict__ cand,
              float* __restrict__ out) {
  __shared__ float smem[256 * 33];     // 33792 B; phase1: xs[32][257]; phase2: qs[256][33]
  __shared__ double lsum[4];
  const int t = threadIdx.x;
  const int blk = blockIdx.x;          // 2048
  const int b = blk >> 5;
  const int hw0 = (blk & 31) * 32;

  // ---- stage x tile [32 rows][256 d]: 32-lane contiguous 128B global reads ----
  {
    const int r = t & 31, dp = t >> 5;           // 8 d-groups
    const float* xb = x + (size_t)b * (EMB_DIM * HW) + hw0 + r;
#pragma unroll
    for (int j = 0; j < 32; ++j) {
      const int d = dp * 32 + j;
      smem[r * XSTR + d] = xb[(size_t)d * HW];
    }
  }
  __syncthreads();

  const int row = t >> 3;              // 0..31
  const int li = t & 7;                // 8 lanes per row
  const int n0 = blk * 32 + row;
  const uint4 ck = *(const uint4*)&cand[(size_t)n0 * 4];
  const uint cv[4] = {ck.x, ck.y, ck.z, ck.w};

  // pull this lane's 32 x-values (d = k*32 + li*4 + e, k=0..7) into registers
  float xf[32];
#pragma unroll
  for (int k = 0; k < 8; ++k)
#pragma unroll
    for (int e = 0; e < 4; ++e)
      xf[k * 4 + e] = smem[row * XSTR + k * 32 + li * 4 + e];
  __syncthreads();   // all xs reads done; smem free for qs reuse

  double sxx = 0.0;
#pragma unroll
  for (int i = 0; i < 32; ++i) sxx = fma((double)xf[i], (double)xf[i], sxx);

  double sj[4], aj[4];
#pragma unroll
  for (int j = 0; j < 4; ++j) {
    const int c = (int)(cv[j] & 1023u);
    const float* wr = w + (size_t)c * EMB_DIM;
    double s = 0.0, a = 0.0;
#pragma unroll
    for (int k = 0; k < 8; ++k) {
      const float4 w4 = *(const float4*)&wr[k * 32 + li * 4];  // 8 lanes x 16B = 128B line
      const float wv[4] = {w4.x, w4.y, w4.z, w4.w};
#pragma unroll
      for (int e = 0; e < 4; ++e) {
        s = fma((double)xf[k * 4 + e], (double)wv[e], s);
        a = fma((double)wv[e], (double)wv[e], a);
      }
    }
    sj[j] = s; aj[j] = a;
  }

  // reduce within 8-lane group (valid at li==0)
#pragma unroll
  for (int o = 4; o; o >>= 1) {
    sxx += __shfl_down(sxx, o);
#pragma unroll
    for (int j = 0; j < 4; ++j) {
      sj[j] += __shfl_down(sj[j], o);
      aj[j] += __shfl_down(aj[j], o);
    }
  }

  double dmin = 0.0;
  int cw = 0;
  if (li == 0) {
    double qbest = -1e300; cw = 1 << 30;
#pragma unroll
    for (int j = 0; j < 4; ++j) {
      const int c = (int)(cv[j] & 1023u);
      const double qj = sj[j] / fmax(sqrt(aj[j]), 1e-12);
      if (qj > qbest || (qj == qbest && c < cw)) { qbest = qj; cw = c; }
    }
    dmin = 2.0 - 2.0 * qbest / fmax(sqrt(sxx), 1e-12);
    out[IDX_OFF + n0] = (float)cw;
  }
  cw = __shfl(cw, (t & 63) & ~7);      // broadcast winner to the row's 8 lanes

  // loss partial: rows at lanes {0,8,...,56}; tree-reduce strides 32,16,8
  double v = dmin;
  v += __shfl_down(v, 32);
  v += __shfl_down(v, 16);
  v += __shfl_down(v, 8);
  if ((t & 63) == 0) lsum[t >> 6] = v;
  __syncthreads();
  if (t == 0)
    atomicAdd(out, (float)(1.25 * (lsum[0] + lsum[1] + lsum[2] + lsum[3]) / 16777216.0));

  // ---- quant: gather wn[cw] (128B/row) -> qs[d][row] -> full-line stores ----
  {
    const float* wr = wn + (size_t)cw * EMB_DIM;
#pragma unroll
    for (int k = 0; k < 8; ++k) {
      const int d0 = k * 32 + li * 4;
      const float4 w4 = *(const float4*)&wr[d0];
      smem[(d0 + 0) * 33 + row] = w4.x;
      smem[(d0 + 1) * 33 + row] = w4.y;
      smem[(d0 + 2) * 33 + row] = w4.z;
      smem[(d0 + 3) * 33 + row] = w4.w;
    }
  }
  __syncthreads();
  {
    const int r = t & 31, dg = t >> 5;     // 8 d-groups of 32
    float* qout = out + QUANT_OFF + (size_t)b * (EMB_DIM * HW) + hw0 + r;
#pragma unroll
    for (int j = 0; j < 32; ++j) {
      const int d = dg * 32 + j;
      qout[(size_t)d * HW] = smem[d * 33 + r];   // 32 lanes x 4B = 128B full line
    }
  }
}

extern "C" void kernel_launch(void* const* d_in, const int* in_sizes, int n_in,
                              void* d_out, int out_size, void* d_ws, size_t ws_size,
                              hipStream_t stream) {
  const float* x = (const float*)d_in[0];   // [64,256,32,32]
  const float* w = (const float*)d_in[1];   // [1024,256]
  float* out = (float*)d_out;               // [1 + 16777216 + 65536] f32

  char* ws = (char*)d_ws;
  float*     wn   = (float*)ws;                      // 1 MB
  _Float16*  wh   = (_Float16*)(ws + 1048576);       // 512 KB
  uint*      cand = (uint*)(ws + 1048576 + 524288);  // 1 MB

  hipMemsetAsync(d_out, 0, sizeof(float), stream);   // zero loss accumulator
  hipLaunchKernelGGL(k_norm_w, dim3(NUM_EMB), dim3(256), 0, stream, w, wn, wh);
  hipLaunchKernelGGL(k_pass1, dim3(N_ROWS / 64), dim3(256), 0, stream, x, wh, cand);
  hipLaunchKernelGGL(k_finish, dim3(N_ROWS / 32), dim3(256), 0, stream, x, w, wn, cand, out);
}

// Round 5
// 213.727 us; speedup vs baseline: 1.7062x; 1.5013x over previous
//
#include <hip/hip_runtime.h>
#include <math.h>

#define NUM_EMB 1024
#define EMB_DIM 256
#define N_ROWS  65536
#define HW      1024
#define QUANT_OFF 1
#define IDX_OFF   (1 + 16777216)
#define LDA 272   // halfs per A-row in LDS: 544B row stride -> 16B aligned, ~2-way banks

typedef unsigned int uint;
typedef _Float16 f16x8 __attribute__((ext_vector_type(8)));
typedef float    f32x4 __attribute__((ext_vector_type(4)));

__device__ __forceinline__ uint umin2(uint a, uint b) { return a < b ? a : b; }
__device__ __forceinline__ uint umax2(uint a, uint b) { return a > b ? a : b; }

__device__ __forceinline__ void load_lds16(const _Float16* g, _Float16* l) {
  __builtin_amdgcn_global_load_lds(
      (const __attribute__((address_space(1))) unsigned int*)g,
      (__attribute__((address_space(3))) unsigned int*)l, 16, 0, 0);
}

// ---- kernel 1: normalize codebook -> wn (f32), wh2 (f16, MFMA-B-swizzled), rinv (f64) ----
// wh2 halfs layout: [chunk(4)][ks(8)][q(4)][code-in-chunk(256)][e(8)], d = ks*32+q*8+e.
__global__ __launch_bounds__(256)
void k_norm_w(const float* __restrict__ w, float* __restrict__ wn,
              _Float16* __restrict__ wh2, double* __restrict__ rinv) {
  const int k = blockIdx.x, t = threadIdx.x;
  const float v = w[(size_t)k * EMB_DIM + t];
  double s = (double)v * (double)v;
  for (int o = 32; o; o >>= 1) s += __shfl_down(s, o);
  __shared__ double ps[4];
  if ((t & 63) == 0) ps[t >> 6] = s;
  __syncthreads();
  const double tot = ps[0] + ps[1] + ps[2] + ps[3];
  const float nv = v / fmaxf((float)sqrt(tot), 1e-12f);
  wn[(size_t)k * EMB_DIM + t] = nv;
  const int chunk = k >> 8, cc = k & 255;
  const int ks = t >> 5, q = (t >> 3) & 3, e = t & 7;
  wh2[(size_t)chunk * 65536 + ks * 8192 + q * 2048 + cc * 8 + e] = (_Float16)nv;
  if (t == 0) rinv[k] = 1.0 / fmax(sqrt(tot), 1e-12);
}

// ---- kernel 2: m97-style fp16 MFMA GEMM (B via async global_load_lds) + top-4 ----
// 1024 blocks x 256 thr. 64 rows/block; 4 chunks of 256 codes (wave w owns 64);
// per chunk: 8 ks-steps of K=32, B-tile 16 KB staged async, 2 barriers/step.
__global__ __launch_bounds__(256)
void k_pass1(const float* __restrict__ x, const _Float16* __restrict__ wh2,
             uint* __restrict__ cand) {
  __shared__ __align__(16) _Float16 As[64 * LDA];   // 34816 B
  __shared__ __align__(16) _Float16 Bs[8192];       // 16384 B: [q(4)][code(256)][8]
  const int t = threadIdx.x;
  const int blk = blockIdx.x;
  const int b = blk >> 4;
  const int hw0 = (blk & 15) * 64;

  // stage A: x[b, d, hw0+r] f32 -> As[r][d] f16
  {
    const int lhw = t & 63;
    const int ph = t >> 6;
    const float* xb = x + (size_t)b * (EMB_DIM * HW) + hw0 + lhw;
#pragma unroll 8
    for (int j = 0; j < 64; ++j) {
      const int d = ph + j * 4;
      As[lhw * LDA + d] = (_Float16)xb[(size_t)d * HW];
    }
  }

  const int lane = t & 63;
  const int q = lane >> 4;
  const int l15 = lane & 15;
  const int w = t >> 6;

  uint t1[16], t2[16];
#pragma unroll
  for (int i = 0; i < 16; ++i) { t1[i] = 0u; t2[i] = 0u; }

  for (int c4 = 0; c4 < 4; ++c4) {
    f32x4 acc[4][4];
#pragma unroll
    for (int rt = 0; rt < 4; ++rt)
#pragma unroll
      for (int ct = 0; ct < 4; ++ct) acc[rt][ct] = (f32x4)0.f;

#pragma unroll 1
    for (int ks = 0; ks < 8; ++ks) {
      __syncthreads();   // previous step's Bs reads done (and A-stage on first pass)
      {
        const _Float16* slab = wh2 + (size_t)c4 * 65536 + ks * 8192 + t * 8;
        _Float16* dst = &Bs[t * 8];
#pragma unroll
        for (int i = 0; i < 4; ++i)
          load_lds16(slab + i * 2048, dst + i * 2048);
      }
      __syncthreads();   // stage complete (vmcnt(0) drained by compiler)

      const f16x8 a0 = *(const f16x8*)&As[(0 * 16 + l15) * LDA + ks * 32 + q * 8];
      const f16x8 a1 = *(const f16x8*)&As[(1 * 16 + l15) * LDA + ks * 32 + q * 8];
      const f16x8 a2 = *(const f16x8*)&As[(2 * 16 + l15) * LDA + ks * 32 + q * 8];
      const f16x8 a3 = *(const f16x8*)&As[(3 * 16 + l15) * LDA + ks * 32 + q * 8];
      const f16x8 b0 = *(const f16x8*)&Bs[q * 2048 + (w * 64 +  0 + l15) * 8];
      const f16x8 b1 = *(const f16x8*)&Bs[q * 2048 + (w * 64 + 16 + l15) * 8];
      const f16x8 b2 = *(const f16x8*)&Bs[q * 2048 + (w * 64 + 32 + l15) * 8];
      const f16x8 b3 = *(const f16x8*)&Bs[q * 2048 + (w * 64 + 48 + l15) * 8];
      acc[0][0] = __builtin_amdgcn_mfma_f32_16x16x32_f16(a0, b0, acc[0][0], 0, 0, 0);
      acc[1][0] = __builtin_amdgcn_mfma_f32_16x16x32_f16(a1, b0, acc[1][0], 0, 0, 0);
      acc[2][0] = __builtin_amdgcn_mfma_f32_16x16x32_f16(a2, b0, acc[2][0], 0, 0, 0);
      acc[3][0] = __builtin_amdgcn_mfma_f32_16x16x32_f16(a3, b0, acc[3][0], 0, 0, 0);
      acc[0][1] = __builtin_amdgcn_mfma_f32_16x16x32_f16(a0, b1, acc[0][1], 0, 0, 0);
      acc[1][1] = __builtin_amdgcn_mfma_f32_16x16x32_f16(a1, b1, acc[1][1], 0, 0, 0);
      acc[2][1] = __builtin_amdgcn_mfma_f32_16x16x32_f16(a2, b1, acc[2][1], 0, 0, 0);
      acc[3][1] = __builtin_amdgcn_mfma_f32_16x16x32_f16(a3, b1, acc[3][1], 0, 0, 0);
      acc[0][2] = __builtin_amdgcn_mfma_f32_16x16x32_f16(a0, b2, acc[0][2], 0, 0, 0);
      acc[1][2] = __builtin_amdgcn_mfma_f32_16x16x32_f16(a1, b2, acc[1][2], 0, 0, 0);
      acc[2][2] = __builtin_amdgcn_mfma_f32_16x16x32_f16(a2, b2, acc[2][2], 0, 0, 0);
      acc[3][2] = __builtin_amdgcn_mfma_f32_16x16x32_f16(a3, b2, acc[3][2], 0, 0, 0);
      acc[0][3] = __builtin_amdgcn_mfma_f32_16x16x32_f16(a0, b3, acc[0][3], 0, 0, 0);
      acc[1][3] = __builtin_amdgcn_mfma_f32_16x16x32_f16(a1, b3, acc[1][3], 0, 0, 0);
      acc[2][3] = __builtin_amdgcn_mfma_f32_16x16x32_f16(a2, b3, acc[2][3], 0, 0, 0);
      acc[3][3] = __builtin_amdgcn_mfma_f32_16x16x32_f16(a3, b3, acc[3][3], 0, 0, 0);
    }

    // merge into per-(lane,slot) top-2 packed keys (score hi-bits | idx)
#pragma unroll
    for (int ct = 0; ct < 4; ++ct) {
      const uint idxv = (uint)(c4 * 256 + w * 64 + ct * 16 + l15);
#pragma unroll
      for (int rt = 0; rt < 4; ++rt)
#pragma unroll
        for (int r = 0; r < 4; ++r) {
          const float v = fmaxf(acc[rt][ct][r], 0.0f);
          const uint key = (__float_as_uint(v) & 0xFFFFFC00u) | idxv;
          const int slot = rt * 4 + r;
          const uint lo = umin2(key, t1[slot]);
          t1[slot] = umax2(key, t1[slot]);
          t2[slot] = umax2(t2[slot], lo);
        }
    }
  }

  // ---- block-level per-row top-4 (reuse A LDS as key scratch) ----
  __syncthreads();
  uint* keys = (uint*)As;   // [64 rows][128 keys] = 32 KB
#pragma unroll
  for (int slot = 0; slot < 16; ++slot) {
    const int rt = slot >> 2, r = slot & 3;
    const int row = rt * 16 + q * 4 + r;
    const int col = w * 32 + l15 * 2;
    keys[row * 128 + col] = t1[slot];
    keys[row * 128 + col + 1] = t2[slot];
  }
  __syncthreads();
  {
    const int row = t >> 2, seg = t & 3;
    uint s1 = 0, s2 = 0;
#pragma unroll
    for (int i = 0; i < 8; ++i) {
      const int ii = (i + t) & 7;
      const uint4 k4 = *(const uint4*)&keys[row * 128 + seg * 32 + ii * 4];
      const uint kk[4] = {k4.x, k4.y, k4.z, k4.w};
#pragma unroll
      for (int e = 0; e < 4; ++e) {
        const uint lo = umin2(kk[e], s1);
        s1 = umax2(kk[e], s1);
        s2 = umax2(s2, lo);
      }
    }
    __syncthreads();
    keys[t * 2] = s1;
    keys[t * 2 + 1] = s2;
  }
  __syncthreads();
  if (t < 64) {
    uint c0 = 0, c1 = 0, c2 = 0, c3 = 0;
#pragma unroll
    for (int i = 0; i < 8; ++i) {
      const uint k = keys[t * 8 + i];
      const uint n0 = umin2(c0, k); c0 = umax2(c0, k);
      const uint n1 = umin2(c1, n0); c1 = umax2(c1, n0);
      const uint n2 = umin2(c2, n1); c2 = umax2(c2, n1);
      c3 = umax2(c3, n2);
    }
    uint4 o; o.x = c0; o.y = c1; o.z = c2; o.w = c3;
    *(uint4*)&cand[(size_t)(blk * 64 + t) * 4] = o;
  }
}

// ------- kernel 3: fp64 recheck (rinv precomputed), idx + loss + quant -------
// 2048 blocks x 256 thr; 32 rows/block; 8 lanes per row.
#define XSTR 257
__global__ __launch_bounds__(256)
void k_finish(const float* __restrict__ x, const float* __restrict__ w,
              const float* __restrict__ wn, const double* __restrict__ rinv,
              const uint* __restrict__ cand, float* __restrict__ out) {
  __shared__ float smem[256 * 33];     // phase1: xs[32][257]; phase2: qs[256][33]
  __shared__ double lsum[4];
  const int t = threadIdx.x;
  const int blk = blockIdx.x;
  const int b = blk >> 5;
  const int hw0 = (blk & 31) * 32;

  // stage x tile [32 rows][256 d]
  {
    const int r = t & 31, dp = t >> 5;
    const float* xb = x + (size_t)b * (EMB_DIM * HW) + hw0 + r;
#pragma unroll
    for (int j = 0; j < 32; ++j) {
      const int d = dp * 32 + j;
      smem[r * XSTR + d] = xb[(size_t)d * HW];
    }
  }
  __syncthreads();

  const int row = t >> 3;
  const int li = t & 7;
  const int n0 = blk * 32 + row;
  const uint4 ck = *(const uint4*)&cand[(size_t)n0 * 4];
  const uint cv[4] = {ck.x, ck.y, ck.z, ck.w};

  float xf[32];
#pragma unroll
  for (int k = 0; k < 8; ++k)
#pragma unroll
    for (int e = 0; e < 4; ++e)
      xf[k * 4 + e] = smem[row * XSTR + k * 32 + li * 4 + e];
  __syncthreads();   // smem free for qs reuse

  double sxx = 0.0;
#pragma unroll
  for (int i = 0; i < 32; ++i) sxx = fma((double)xf[i], (double)xf[i], sxx);

  double sj[4];
#pragma unroll
  for (int j = 0; j < 4; ++j) {
    const int c = (int)(cv[j] & 1023u);
    const float* wr = w + (size_t)c * EMB_DIM;
    double s = 0.0;
#pragma unroll
    for (int k = 0; k < 8; ++k) {
      const float4 w4 = *(const float4*)&wr[k * 32 + li * 4];
      const float wv[4] = {w4.x, w4.y, w4.z, w4.w};
#pragma unroll
      for (int e = 0; e < 4; ++e)
        s = fma((double)xf[k * 4 + e], (double)wv[e], s);
    }
    sj[j] = s;
  }

#pragma unroll
  for (int o = 4; o; o >>= 1) {
    sxx += __shfl_down(sxx, o);
#pragma unroll
    for (int j = 0; j < 4; ++j) sj[j] += __shfl_down(sj[j], o);
  }

  double dmin = 0.0;
  int cw = 0;
  if (li == 0) {
    double qbest = -1e300; cw = 1 << 30;
#pragma unroll
    for (int j = 0; j < 4; ++j) {
      const int c = (int)(cv[j] & 1023u);
      const double qj = sj[j] * rinv[c];
      if (qj > qbest || (qj == qbest && c < cw)) { qbest = qj; cw = c; }
    }
    dmin = 2.0 - 2.0 * qbest / fmax(sqrt(sxx), 1e-12);
    out[IDX_OFF + n0] = (float)cw;
  }
  cw = __shfl(cw, (t & 63) & ~7);

  double v = dmin;
  v += __shfl_down(v, 32);
  v += __shfl_down(v, 16);
  v += __shfl_down(v, 8);
  if ((t & 63) == 0) lsum[t >> 6] = v;
  __syncthreads();
  if (t == 0)
    atomicAdd(out, (float)(1.25 * (lsum[0] + lsum[1] + lsum[2] + lsum[3]) / 16777216.0));

  // quant: gather wn[cw] (128B/row) -> qs[d][row(32)+pad] -> float4 coalesced stores
  {
    const float* wr = wn + (size_t)cw * EMB_DIM;
#pragma unroll
    for (int k = 0; k < 8; ++k) {
      const int d0 = k * 32 + li * 4;
      const float4 w4 = *(const float4*)&wr[d0];
      smem[(d0 + 0) * 33 + row] = w4.x;
      smem[(d0 + 1) * 33 + row] = w4.y;
      smem[(d0 + 2) * 33 + row] = w4.z;
      smem[(d0 + 3) * 33 + row] = w4.w;
    }
  }
  __syncthreads();
  {
    const int hw4 = (t & 7) * 4, dbase = t >> 3;   // 32 d-groups of 8
    float* qout = out + QUANT_OFF + (size_t)b * (EMB_DIM * HW) + hw0;
#pragma unroll
    for (int jj = 0; jj < 8; ++jj) {
      const int d = jj * 32 + dbase;
      float4 v4;
      v4.x = smem[d * 33 + hw4 + 0];
      v4.y = smem[d * 33 + hw4 + 1];
      v4.z = smem[d * 33 + hw4 + 2];
      v4.w = smem[d * 33 + hw4 + 3];
      *(float4*)&qout[(size_t)d * HW + hw4] = v4;
    }
  }
}

extern "C" void kernel_launch(void* const* d_in, const int* in_sizes, int n_in,
                              void* d_out, int out_size, void* d_ws, size_t ws_size,
                              hipStream_t stream) {
  const float* x = (const float*)d_in[0];   // [64,256,32,32]
  const float* w = (const float*)d_in[1];   // [1024,256]
  float* out = (float*)d_out;               // [1 + 16777216 + 65536] f32

  char* ws = (char*)d_ws;
  float*     wn   = (float*)ws;                                // 1 MB
  _Float16*  wh2  = (_Float16*)(ws + 1048576);                 // 512 KB (swizzled)
  double*    rinv = (double*)(ws + 1048576 + 524288);          // 8 KB
  uint*      cand = (uint*)(ws + 1048576 + 524288 + 8192);     // 1 MB

  hipMemsetAsync(d_out, 0, sizeof(float), stream);   // zero loss accumulator
  hipLaunchKernelGGL(k_norm_w, dim3(NUM_EMB), dim3(256), 0, stream, w, wn, wh2, rinv);
  hipLaunchKernelGGL(k_pass1, dim3(N_ROWS / 64), dim3(256), 0, stream, x, wh2, cand);
  hipLaunchKernelGGL(k_finish, dim3(N_ROWS / 32), dim3(256), 0, stream, x, w, wn, rinv, cand, out);
}